// Round 1
// baseline (454.573 us; speedup 1.0000x reference)
//
#include <hip/hip_runtime.h>

// Residual GCN, MI355X. B=8, N=2048, D=128 fixed. External dtype fp32.
// out = dinv_i * (A @ (dinv_j * leakyrelu(X@W + b))) [+ X]
// Internal pipeline bf16 + MFMA 16x16x32 bf16, fp32 accumulate.
//
// R9: occupancy/latency attack on both GEMM kernels.
//  Old k_gxw/k_gah: 256 blocks = 1 block/CU = 1 wave/SIMD, and k_gah ran a
//  __syncthreads-per-K-tile LDS pipeline whose compiler-inserted
//  vmcnt(0)+lgkmcnt(0) drain exposed full L2/HBM latency every step.
//  New: barrier-free streaming GEMMs. B operands are cache-resident
//  (HsT = 512 KB/batch in its XCD's L2 via the b = bb&7 affinity; WT = 32 KB),
//  so B-fragments are read straight from L2 instead of LDS. 2048 independent
//  waves (512 blocks -> 2 blocks/CU -> 2 waves/SIMD), 1-step register
//  ping-pong prefetch, ZERO __syncthreads in the K loop.
//  Block's 4 waves = {2 row-tiles} x {2 col-halves}: col-half pairs share A
//  lines in L1, row-tile pairs share B lines.
//  ws layout reordered (adjb first) so the unconditional last-iter prefetch
//  over-read (<= a few KB past each region's logical end, values discarded)
//  lands inside the workspace.
// Numerics identical to R4 (same accumulation order / bf16 casts).

typedef short bf16x8 __attribute__((ext_vector_type(8)));
typedef float f32x4 __attribute__((ext_vector_type(4)));

static __device__ __forceinline__ float bf2f(unsigned short h) {
    union { unsigned int u; float f; } v; v.u = ((unsigned int)h) << 16; return v.f;
}
static __device__ __forceinline__ unsigned short f2bf(float x) {  // RNE
    union { float f; unsigned int u; } v; v.f = x;
    return (unsigned short)((v.u + 0x7FFFu + ((v.u >> 16) & 1u)) >> 16);
}

// ---- fused: adj rowsum -> dinv, adj fp32 -> bf16, W transpose, bias ------
__global__ __launch_bounds__(256) void k_pre(const float* __restrict__ adj,
                                             const float* __restrict__ W1,
                                             const float* __restrict__ W2,
                                             const float* __restrict__ W3,
                                             const float* __restrict__ b1,
                                             const float* __restrict__ b2,
                                             const float* __restrict__ b3,
                                             float* __restrict__ dinv,
                                             unsigned short* __restrict__ adjb,
                                             unsigned short* __restrict__ WT,
                                             float* __restrict__ biasf) {
    if (blockIdx.x >= 16384) {                        // prep tail: W^T + bias
        const int e = (blockIdx.x - 16384) * 256 + threadIdx.x;
        if (e < 49152) {
            const int w = e >> 14, r = e & 16383;
            const int f = r & 127, k = r >> 7;
            const float* W = (w == 0) ? W1 : ((w == 1) ? W2 : W3);
            WT[w * 16384 + f * 128 + k] = f2bf(W[r]);
        } else if (e < 49536) {
            const int idx = e - 49152;
            const float* bp = (idx < 128) ? b1 : ((idx < 256) ? b2 : b3);
            biasf[idx] = bp[idx & 127];
        }
        return;
    }
    const int row = blockIdx.x;                       // 0..16383
    const size_t base = (size_t)row * 2048 + threadIdx.x * 8;
    const float4 a = *(const float4*)(adj + base);
    const float4 b = *(const float4*)(adj + base + 4);
    float s = a.x + a.y + a.z + a.w + b.x + b.y + b.z + b.w;
    union { uint4 u; unsigned short h[8]; } pk;
    pk.h[0] = f2bf(a.x); pk.h[1] = f2bf(a.y); pk.h[2] = f2bf(a.z); pk.h[3] = f2bf(a.w);
    pk.h[4] = f2bf(b.x); pk.h[5] = f2bf(b.y); pk.h[6] = f2bf(b.z); pk.h[7] = f2bf(b.w);
    *(uint4*)(adjb + base) = pk.u;
#pragma unroll
    for (int off = 32; off > 0; off >>= 1) s += __shfl_down(s, off);
    __shared__ float ws[4];
    if ((threadIdx.x & 63) == 0) ws[threadIdx.x >> 6] = s;
    __syncthreads();
    if (threadIdx.x == 0) {
        float t = ws[0] + ws[1] + ws[2] + ws[3];
        dinv[row] = (t > 0.f) ? rsqrtf(t) : 0.f;      // matches where(isinf,0)
    }
}

// ---- small GEMM: Hs = leakyrelu(X @ W + b) * dinv_j -> HsT (transposed) --
// Barrier-free: W-fragments straight from L2-hot WT (32 KB). 2048 waves,
// each 16 rows x 64 cols, K=128 fully unrolled.
template <int AEXT>
__global__ __launch_bounds__(256) void k_gxw(const void* __restrict__ Asrc,
                                             const unsigned short* __restrict__ WTb,
                                             const float* __restrict__ biasf,
                                             const float* __restrict__ dinv,
                                             unsigned short* __restrict__ HsT) {
    const int tid  = threadIdx.x;
    const int wave = tid >> 6;
    const int lane = tid & 63;
    const int n_   = lane & 15;
    const int q    = lane >> 4;

    const int u  = blockIdx.x * 4 + wave;             // 0..2047 (512 blocks)
    const int rt = u >> 1;                            // row tile 0..1023
    const int ch = u & 1;                             // col half 0..1
    const int arow = rt * 16 + n_;                    // global row 0..16383

    f32x4 acc[4];
#pragma unroll
    for (int i = 0; i < 4; ++i) acc[i] = (f32x4){0.f, 0.f, 0.f, 0.f};

#pragma unroll
    for (int s = 0; s < 4; ++s) {                     // K = 4 x 32
        bf16x8 a;
        if (AEXT) {
            const float* p = (const float*)Asrc + (size_t)arow * 128 + s * 32 + q * 8;
            float4 uu = ((const float4*)p)[0], w = ((const float4*)p)[1];
            union { bf16x8 v; unsigned short h[8]; } r;
            r.h[0] = f2bf(uu.x); r.h[1] = f2bf(uu.y); r.h[2] = f2bf(uu.z); r.h[3] = f2bf(uu.w);
            r.h[4] = f2bf(w.x);  r.h[5] = f2bf(w.y);  r.h[6] = f2bf(w.z);  r.h[7] = f2bf(w.w);
            a = r.v;
        } else {
            a = *(const bf16x8*)((const unsigned short*)Asrc + (size_t)arow * 128 + s * 32 + q * 8);
        }
#pragma unroll
        for (int nt = 0; nt < 4; ++nt) {
            const int f = ch * 64 + nt * 16 + n_;
            bf16x8 bv = *(const bf16x8*)(WTb + f * 128 + s * 32 + q * 8);
            acc[nt] = __builtin_amdgcn_mfma_f32_16x16x32_bf16(a, bv, acc[nt], 0, 0, 0);
        }
    }

    // C/D: col = lane&15, row = quad*4 + reg
    const int rbase = rt * 16 + q * 4;                // global row base
    float dsc[4];
#pragma unroll
    for (int r = 0; r < 4; ++r) dsc[r] = dinv[rbase + r];
    const int b  = rbase >> 11;
    const int jb = rbase & 2047;
    unsigned short* Hb = HsT + (size_t)b * (128 * 2048);
#pragma unroll
    for (int nt = 0; nt < 4; ++nt) {
        const int f = ch * 64 + nt * 16 + n_;
        const float bf = biasf[f];
        unsigned short pk[4];
#pragma unroll
        for (int r = 0; r < 4; ++r) {
            float v = acc[nt][r] + bf;
            v = (v > 0.f) ? v : 0.01f * v;            // LeakyReLU(0.01)
            pk[r] = f2bf(v * dsc[r]);                 // * dinv_j
        }
        uint2 uo;
        uo.x = (unsigned int)pk[0] | ((unsigned int)pk[1] << 16);
        uo.y = (unsigned int)pk[2] | ((unsigned int)pk[3] << 16);
        *(uint2*)(Hb + (size_t)f * 2048 + jb) = uo;   // HsT[b][f][j]
    }
}

// ---- big GEMM: out = (adjb @ HsT^T) * dinv_i [+resid] --------------------
// Barrier-free streaming: 2048 waves (512 blocks, 2 blocks/CU), each owns a
// 16-row x 64-col tile with K=2048. A streams from adjb (L3/HBM); B-frags
// are read straight from HsT in the batch's XCD L2. 1-step register
// ping-pong prefetch; no LDS, no __syncthreads.
// MODE 1: store (*dinv_i); MODE 2: +resid. OUT32: fp32 store else bf16.
template <int MODE, int OUT32>
__global__ __launch_bounds__(256) void k_gah(const unsigned short* __restrict__ adjb,
                                             const unsigned short* __restrict__ HsT,
                                             const float* __restrict__ dinv,
                                             const unsigned short* __restrict__ resid,
                                             void* __restrict__ outp) {
    const int tid  = threadIdx.x;
    const int wave = tid >> 6;
    const int lane = tid & 63;
    const int n_   = lane & 15;
    const int q    = lane >> 4;

    const int bb = blockIdx.x;                        // 512 blocks
    const int b  = bb & 7;                            // batch -> XCD affinity
    const int u  = (bb >> 3) * 4 + wave;              // 0..255 within batch
    const int rt = u >> 1;                            // row tile 0..127
    const int ch = u & 1;                             // col half 0..1
    const int row0 = b * 2048 + rt * 16;

    const unsigned short* Ap = adjb + (size_t)(row0 + n_) * 2048 + q * 8;
    const unsigned short* Bp = HsT + (size_t)b * (128 * 2048)
                             + (size_t)(ch * 64 + n_) * 2048 + q * 8;

    f32x4 acc[4];
#pragma unroll
    for (int i = 0; i < 4; ++i) acc[i] = (f32x4){0.f, 0.f, 0.f, 0.f};

    // K loop: 2 half-steps (K=32 each) per iteration, explicit ping-pong so
    // the next half-step's loads are always in flight under current MFMAs.
    bf16x8 a0, a1, b00, b01, b02, b03, b10, b11, b12, b13;
    a0  = *(const bf16x8*)(Ap);
    b00 = *(const bf16x8*)(Bp);
    b01 = *(const bf16x8*)(Bp + 32768);
    b02 = *(const bf16x8*)(Bp + 65536);
    b03 = *(const bf16x8*)(Bp + 98304);
#pragma unroll 1
    for (int k = 0; k < 2048; k += 64) {
        a1  = *(const bf16x8*)(Ap + k + 32);
        b10 = *(const bf16x8*)(Bp + k + 32);
        b11 = *(const bf16x8*)(Bp + 32768 + k + 32);
        b12 = *(const bf16x8*)(Bp + 65536 + k + 32);
        b13 = *(const bf16x8*)(Bp + 98304 + k + 32);
        acc[0] = __builtin_amdgcn_mfma_f32_16x16x32_bf16(a0, b00, acc[0], 0, 0, 0);
        acc[1] = __builtin_amdgcn_mfma_f32_16x16x32_bf16(a0, b01, acc[1], 0, 0, 0);
        acc[2] = __builtin_amdgcn_mfma_f32_16x16x32_bf16(a0, b02, acc[2], 0, 0, 0);
        acc[3] = __builtin_amdgcn_mfma_f32_16x16x32_bf16(a0, b03, acc[3], 0, 0, 0);
        // final iteration over-reads <=64 elems past the logical row end;
        // lands in the next ws region (values never consumed).
        a0  = *(const bf16x8*)(Ap + k + 64);
        b00 = *(const bf16x8*)(Bp + k + 64);
        b01 = *(const bf16x8*)(Bp + 32768 + k + 64);
        b02 = *(const bf16x8*)(Bp + 65536 + k + 64);
        b03 = *(const bf16x8*)(Bp + 98304 + k + 64);
        acc[0] = __builtin_amdgcn_mfma_f32_16x16x32_bf16(a1, b10, acc[0], 0, 0, 0);
        acc[1] = __builtin_amdgcn_mfma_f32_16x16x32_bf16(a1, b11, acc[1], 0, 0, 0);
        acc[2] = __builtin_amdgcn_mfma_f32_16x16x32_bf16(a1, b12, acc[2], 0, 0, 0);
        acc[3] = __builtin_amdgcn_mfma_f32_16x16x32_bf16(a1, b13, acc[3], 0, 0, 0);
    }

    // epilogue. C/D: col = lane&15, row = quad*4 + reg
    const int rb = row0 + q * 4;
    float dsc[4];
#pragma unroll
    for (int r = 0; r < 4; ++r) dsc[r] = dinv[rb + r];
#pragma unroll
    for (int nt = 0; nt < 4; ++nt) {
        const int f = ch * 64 + nt * 16 + n_;
#pragma unroll
        for (int r = 0; r < 4; ++r) {
            const size_t gr = (size_t)(rb + r);
            float v = acc[nt][r] * dsc[r];            // * dinv_i
            if (MODE == 2) v += bf2f(resid[gr * 128 + f]);
            if (OUT32) ((float*)outp)[gr * 128 + f] = v;
            else ((unsigned short*)outp)[gr * 128 + f] = f2bf(v);
        }
    }
}

extern "C" void kernel_launch(void* const* d_in, const int* in_sizes, int n_in,
                              void* d_out, int out_size, void* d_ws, size_t ws_size,
                              hipStream_t stream) {
    const float* X   = (const float*)d_in[0];
    const float* adj = (const float*)d_in[1];
    const float* W1  = (const float*)d_in[2];
    const float* b1  = (const float*)d_in[3];
    const float* W2  = (const float*)d_in[4];
    const float* b2  = (const float*)d_in[5];
    const float* W3  = (const float*)d_in[6];
    const float* b3  = (const float*)d_in[7];

    // ws: adjb @0 (64 MiB) | dinv @64M (64K) | biasf @64M+64K | WT @64M+128K
    //     (96K) | HsT @64M+256K (4M) | Xa @68M+256K (4M) | X2 @72M+256K (4M)
    // adjb first so its tail is followed by other regions (prefetch over-read
    // stays in-bounds).
    char* ws = (char*)d_ws;
    unsigned short* adjb  = (unsigned short*)ws;
    float*          dinv  = (float*)(ws + (64u << 20));
    float*          biasf = (float*)(ws + (64u << 20) + (64u << 10));
    unsigned short* WT    = (unsigned short*)(ws + (64u << 20) + (128u << 10));
    unsigned short* HsT   = (unsigned short*)(ws + (64u << 20) + (256u << 10));
    unsigned short* Xa    = (unsigned short*)(ws + (68u << 20) + (256u << 10));
    unsigned short* X2    = (unsigned short*)(ws + (72u << 20) + (256u << 10));

    k_pre<<<16578, 256, 0, stream>>>(adj, W1, W2, W3, b1, b2, b3, dinv, adjb, WT, biasf);

    // layer 1
    k_gxw<1><<<512, 256, 0, stream>>>(X, WT, biasf, dinv, HsT);
    k_gah<1, 0><<<512, 256, 0, stream>>>(adjb, HsT, dinv, nullptr, Xa);
    // layer 2 (residual = Xa)
    k_gxw<0><<<512, 256, 0, stream>>>(Xa, WT + 16384, biasf + 128, dinv, HsT);
    k_gah<2, 0><<<512, 256, 0, stream>>>(adjb, HsT, dinv, Xa, X2);
    // layer 3 -> fp32 out
    k_gxw<0><<<512, 256, 0, stream>>>(X2, WT + 32768, biasf + 256, dinv, HsT);
    k_gah<1, 1><<<512, 256, 0, stream>>>(adjb, HsT, dinv, nullptr, (float*)d_out);
}

// Round 2
// 289.806 us; speedup vs baseline: 1.5685x; 1.5685x over previous
//
#include <hip/hip_runtime.h>

// Residual GCN, MI355X. B=8, N=2048, D=128 fixed. External dtype fp32.
// out = dinv_i * (A @ (dinv_j * leakyrelu(X@W + b))) [+ X]
// Internal pipeline bf16 + MFMA 16x16x32 bf16, fp32 accumulate.
//
// R10: back to LDS-shared-B double-buffered GEMMs, with 2 blocks/CU.
//  R9 post-mortem: barrier-free streaming k_gah measured 77 us with
//  MfmaUtil 4%, VALU 6%, HBM 7%, occupancy 20% -> pure latency-bound
//  (depth-1 prefetch covers ~40 cyc of ~400 cyc L2 latency; 2 waves/SIMD
//  can't TLP over it; 512 MB of per-wave-private HsT re-reads from L2).
//  Fix: share B through LDS again (m97-family structure: reg-staged,
//  padded, double-buffered, ONE barrier per K-step, prefetch issued at
//  step top), but at 32x128 tiles -> 512 blocks = 2 blocks/CU so the
//  per-step barrier drain of one block overlaps the other block's compute
//  (R8's 64x128/256-block version was 1 block/CU -> nothing to overlap).
//  k_gxw: stage WT (32 KB) in LDS once, one barrier, then barrier-free
//  MFMA burst; 512 blocks.
// Numerics identical to R4/R9 (same accumulation order / bf16 casts).

typedef short bf16x8 __attribute__((ext_vector_type(8)));
typedef float f32x4 __attribute__((ext_vector_type(4)));

static __device__ __forceinline__ float bf2f(unsigned short h) {
    union { unsigned int u; float f; } v; v.u = ((unsigned int)h) << 16; return v.f;
}
static __device__ __forceinline__ unsigned short f2bf(float x) {  // RNE
    union { float f; unsigned int u; } v; v.f = x;
    return (unsigned short)((v.u + 0x7FFFu + ((v.u >> 16) & 1u)) >> 16);
}

// ---- fused: adj rowsum -> dinv, adj fp32 -> bf16, W transpose, bias ------
__global__ __launch_bounds__(256) void k_pre(const float* __restrict__ adj,
                                             const float* __restrict__ W1,
                                             const float* __restrict__ W2,
                                             const float* __restrict__ W3,
                                             const float* __restrict__ b1,
                                             const float* __restrict__ b2,
                                             const float* __restrict__ b3,
                                             float* __restrict__ dinv,
                                             unsigned short* __restrict__ adjb,
                                             unsigned short* __restrict__ WT,
                                             float* __restrict__ biasf) {
    if (blockIdx.x >= 16384) {                        // prep tail: W^T + bias
        const int e = (blockIdx.x - 16384) * 256 + threadIdx.x;
        if (e < 49152) {
            const int w = e >> 14, r = e & 16383;
            const int f = r & 127, k = r >> 7;
            const float* W = (w == 0) ? W1 : ((w == 1) ? W2 : W3);
            WT[w * 16384 + f * 128 + k] = f2bf(W[r]);
        } else if (e < 49536) {
            const int idx = e - 49152;
            const float* bp = (idx < 128) ? b1 : ((idx < 256) ? b2 : b3);
            biasf[idx] = bp[idx & 127];
        }
        return;
    }
    const int row = blockIdx.x;                       // 0..16383
    const size_t base = (size_t)row * 2048 + threadIdx.x * 8;
    const float4 a = *(const float4*)(adj + base);
    const float4 b = *(const float4*)(adj + base + 4);
    float s = a.x + a.y + a.z + a.w + b.x + b.y + b.z + b.w;
    union { uint4 u; unsigned short h[8]; } pk;
    pk.h[0] = f2bf(a.x); pk.h[1] = f2bf(a.y); pk.h[2] = f2bf(a.z); pk.h[3] = f2bf(a.w);
    pk.h[4] = f2bf(b.x); pk.h[5] = f2bf(b.y); pk.h[6] = f2bf(b.z); pk.h[7] = f2bf(b.w);
    *(uint4*)(adjb + base) = pk.u;
#pragma unroll
    for (int off = 32; off > 0; off >>= 1) s += __shfl_down(s, off);
    __shared__ float ws[4];
    if ((threadIdx.x & 63) == 0) ws[threadIdx.x >> 6] = s;
    __syncthreads();
    if (threadIdx.x == 0) {
        float t = ws[0] + ws[1] + ws[2] + ws[3];
        dinv[row] = (t > 0.f) ? rsqrtf(t) : 0.f;      // matches where(isinf,0)
    }
}

// ---- small GEMM: Hs = leakyrelu(X @ W + b) * dinv_j -> HsT (transposed) --
// Stage full 128x128 WT in LDS once (one barrier), then barrier-free MFMA.
// 512 blocks x 4 waves; block = 32 rows; wave = 16 rows x 64 f.
template <int AEXT>
__global__ __launch_bounds__(256) void k_gxw(const void* __restrict__ Asrc,
                                             const unsigned short* __restrict__ WTb,
                                             const float* __restrict__ biasf,
                                             const float* __restrict__ dinv,
                                             unsigned short* __restrict__ HsT) {
    constexpr int LDK = 136;                          // 128 + 8 pad
    __shared__ unsigned short Bs[128 * LDK];          // 34 KB

    const int tid  = threadIdx.x;
    const int wave = tid >> 6;
    const int lane = tid & 63;
    const int n_   = lane & 15;
    const int q    = lane >> 4;
    const int wm   = wave >> 1;                       // row half 0..1
    const int ch   = wave & 1;                        // col half 0..1

    const int r0 = blockIdx.x * 32;                   // 512 blocks

#pragma unroll
    for (int it = 0; it < 8; ++it) {                  // stage full 128x128 WT
        int task = tid + it * 256;
        int f  = task >> 4;
        int cj = (task & 15) * 8;
        *(uint4*)(&Bs[f * LDK + cj]) = *(const uint4*)(WTb + f * 128 + cj);
    }
    __syncthreads();

    const int arow = r0 + wm * 16 + n_;
    bf16x8 av[4];
#pragma unroll
    for (int s = 0; s < 4; ++s) {
        if (AEXT) {
            const float* p = (const float*)Asrc + (size_t)arow * 128 + s * 32 + q * 8;
            float4 uu = ((const float4*)p)[0], w = ((const float4*)p)[1];
            union { bf16x8 v; unsigned short h[8]; } r;
            r.h[0] = f2bf(uu.x); r.h[1] = f2bf(uu.y); r.h[2] = f2bf(uu.z); r.h[3] = f2bf(uu.w);
            r.h[4] = f2bf(w.x);  r.h[5] = f2bf(w.y);  r.h[6] = f2bf(w.z);  r.h[7] = f2bf(w.w);
            av[s] = r.v;
        } else {
            av[s] = *(const bf16x8*)((const unsigned short*)Asrc + (size_t)arow * 128 + s * 32 + q * 8);
        }
    }

    f32x4 acc[4];
#pragma unroll
    for (int i = 0; i < 4; ++i) acc[i] = (f32x4){0.f, 0.f, 0.f, 0.f};
#pragma unroll
    for (int s = 0; s < 4; ++s) {
#pragma unroll
        for (int nt = 0; nt < 4; ++nt) {
            bf16x8 bv = *(const bf16x8*)(&Bs[(ch * 64 + nt * 16 + n_) * LDK + s * 32 + q * 8]);
            acc[nt] = __builtin_amdgcn_mfma_f32_16x16x32_bf16(av[s], bv, acc[nt], 0, 0, 0);
        }
    }

    // C/D: col = lane&15, row = quad*4 + reg
    const int rbase = r0 + wm * 16 + q * 4;
    float dsc[4];
#pragma unroll
    for (int r = 0; r < 4; ++r) dsc[r] = dinv[rbase + r];
    const int b  = rbase >> 11;
    const int jb = rbase & 2047;
    unsigned short* Hb = HsT + (size_t)b * (128 * 2048);
#pragma unroll
    for (int nt = 0; nt < 4; ++nt) {
        const int f = ch * 64 + nt * 16 + n_;
        const float bf = biasf[f];
        unsigned short pk[4];
#pragma unroll
        for (int r = 0; r < 4; ++r) {
            float v = acc[nt][r] + bf;
            v = (v > 0.f) ? v : 0.01f * v;            // LeakyReLU(0.01)
            pk[r] = f2bf(v * dsc[r]);                 // * dinv_j
        }
        uint2 uo;
        uo.x = (unsigned int)pk[0] | ((unsigned int)pk[1] << 16);
        uo.y = (unsigned int)pk[2] | ((unsigned int)pk[3] << 16);
        *(uint2*)(Hb + (size_t)f * 2048 + jb) = uo;   // HsT[b][f][j]
    }
}

// ---- big GEMM: out = (adjb @ HsT^T) * dinv_i [+resid] --------------------
// 512 blocks (2/CU), block = 32 rows x 128 f, K = 2048 in 32 steps of 64.
// Reg-staged padded LDS double-buffer, ONE barrier per step, prefetch
// issued at step top so global latency hides under ds_read + MFMA; the
// second resident block covers the barrier drain.
// Wave w: 32 rows x 32 f (f in [w*32, w*32+32)), acc 2x2 16x16 frags.
// MODE 1: store (*dinv_i); MODE 2: +resid. OUT32: fp32 store else bf16.
template <int MODE, int OUT32>
__global__ __launch_bounds__(256) void k_gah(const unsigned short* __restrict__ adjb,
                                             const unsigned short* __restrict__ HsT,
                                             const float* __restrict__ dinv,
                                             const unsigned short* __restrict__ resid,
                                             void* __restrict__ outp) {
    constexpr int LDK = 72;                           // 64 + 8 pad
    constexpr int ASZ = 32 * LDK;                     // 2304 elems
    constexpr int BSZ = 128 * LDK;                    // 9216 elems
    __shared__ unsigned short Sm[2 * (ASZ + BSZ)];    // 46 KB -> 2-3 blk/CU

    const int tid  = threadIdx.x;
    const int wave = tid >> 6;
    const int lane = tid & 63;
    const int n_   = lane & 15;
    const int q    = lane >> 4;

    const int bb = blockIdx.x;                        // 512 blocks
    const int b  = bb & 7;                            // batch -> XCD affinity
    const int rt = bb >> 3;                           // 0..63
    const int row0 = b * 2048 + rt * 32;

    const unsigned short* Ag = adjb + (size_t)row0 * 2048;
    const unsigned short* Bg = HsT + (size_t)b * (128 * 2048);

    // staging: thread t -> A row t>>3 (1 chunk) + B rows (t>>3)+{0,32,64,96}
    const int srow = tid >> 3;                        // 0..31
    const int sc   = (tid & 7) * 8;                   // 0..56
    const unsigned short* As = Ag + (size_t)srow * 2048 + sc;
    const unsigned short* Bsc = Bg + (size_t)srow * 2048 + sc;
    const int dA = srow * LDK + sc;
    const int dB = ASZ + srow * LDK + sc;

    // prologue: stage tile 0
    uint4 rA, rB0, rB1, rB2, rB3;
    rA  = *(const uint4*)(As);
    rB0 = *(const uint4*)(Bsc);
    rB1 = *(const uint4*)(Bsc + 32 * 2048);
    rB2 = *(const uint4*)(Bsc + 64 * 2048);
    rB3 = *(const uint4*)(Bsc + 96 * 2048);
    *(uint4*)(&Sm[dA]) = rA;
    *(uint4*)(&Sm[dB]) = rB0;
    *(uint4*)(&Sm[dB + 32 * LDK]) = rB1;
    *(uint4*)(&Sm[dB + 64 * LDK]) = rB2;
    *(uint4*)(&Sm[dB + 96 * LDK]) = rB3;
    __syncthreads();

    f32x4 acc[2][2];
#pragma unroll
    for (int i = 0; i < 2; ++i)
#pragma unroll
        for (int j = 0; j < 2; ++j) acc[i][j] = (f32x4){0.f, 0.f, 0.f, 0.f};

    const int aoff = n_ * LDK + q * 8;                // A frag base (row n_)
    const int boff = ASZ + (wave * 32 + n_) * LDK + q * 8;

#pragma unroll 1
    for (int kc = 0; kc < 32; ++kc) {
        const int cur = kc & 1;
        if (kc < 31) {                                // issue next-tile loads
            const int kn = (kc + 1) * 64;
            rA  = *(const uint4*)(As + kn);
            rB0 = *(const uint4*)(Bsc + kn);
            rB1 = *(const uint4*)(Bsc + 32 * 2048 + kn);
            rB2 = *(const uint4*)(Bsc + 64 * 2048 + kn);
            rB3 = *(const uint4*)(Bsc + 96 * 2048 + kn);
        }
        const unsigned short* sb = &Sm[cur * (ASZ + BSZ)];
#pragma unroll
        for (int s = 0; s < 2; ++s) {
            bf16x8 a0 = *(const bf16x8*)(&sb[aoff + s * 32]);
            bf16x8 a1 = *(const bf16x8*)(&sb[aoff + 16 * LDK + s * 32]);
            bf16x8 b0 = *(const bf16x8*)(&sb[boff + s * 32]);
            bf16x8 b1 = *(const bf16x8*)(&sb[boff + 16 * LDK + s * 32]);
            acc[0][0] = __builtin_amdgcn_mfma_f32_16x16x32_bf16(a0, b0, acc[0][0], 0, 0, 0);
            acc[1][0] = __builtin_amdgcn_mfma_f32_16x16x32_bf16(a1, b0, acc[1][0], 0, 0, 0);
            acc[0][1] = __builtin_amdgcn_mfma_f32_16x16x32_bf16(a0, b1, acc[0][1], 0, 0, 0);
            acc[1][1] = __builtin_amdgcn_mfma_f32_16x16x32_bf16(a1, b1, acc[1][1], 0, 0, 0);
        }
        if (kc < 31) {                                // write next buffer
            unsigned short* sw = &Sm[(cur ^ 1) * (ASZ + BSZ)];
            *(uint4*)(&sw[dA]) = rA;
            *(uint4*)(&sw[dB]) = rB0;
            *(uint4*)(&sw[dB + 32 * LDK]) = rB1;
            *(uint4*)(&sw[dB + 64 * LDK]) = rB2;
            *(uint4*)(&sw[dB + 96 * LDK]) = rB3;
        }
        __syncthreads();
    }

    // epilogue. C/D: col = lane&15, row = quad*4 + reg
    const int rb = row0 + q * 4;
    float dsc[2][4];
#pragma unroll
    for (int mi = 0; mi < 2; ++mi)
#pragma unroll
        for (int r = 0; r < 4; ++r) dsc[mi][r] = dinv[rb + mi * 16 + r];
#pragma unroll
    for (int mi = 0; mi < 2; ++mi) {
#pragma unroll
        for (int nj = 0; nj < 2; ++nj) {
            const int f = wave * 32 + nj * 16 + n_;
#pragma unroll
            for (int r = 0; r < 4; ++r) {
                const size_t gr = (size_t)(rb + mi * 16 + r);
                float v = acc[mi][nj][r] * dsc[mi][r];    // * dinv_i
                if (MODE == 2) v += bf2f(resid[gr * 128 + f]);
                if (OUT32) ((float*)outp)[gr * 128 + f] = v;
                else ((unsigned short*)outp)[gr * 128 + f] = f2bf(v);
            }
        }
    }
}

extern "C" void kernel_launch(void* const* d_in, const int* in_sizes, int n_in,
                              void* d_out, int out_size, void* d_ws, size_t ws_size,
                              hipStream_t stream) {
    const float* X   = (const float*)d_in[0];
    const float* adj = (const float*)d_in[1];
    const float* W1  = (const float*)d_in[2];
    const float* b1  = (const float*)d_in[3];
    const float* W2  = (const float*)d_in[4];
    const float* b2  = (const float*)d_in[5];
    const float* W3  = (const float*)d_in[6];
    const float* b3  = (const float*)d_in[7];

    // ws: adjb @0 (64 MiB) | dinv @64M (64K) | biasf @64M+64K | WT @64M+128K
    //     (96K) | HsT @64M+256K (4M) | Xa @68M+256K (4M) | X2 @72M+256K (4M)
    char* ws = (char*)d_ws;
    unsigned short* adjb  = (unsigned short*)ws;
    float*          dinv  = (float*)(ws + (64u << 20));
    float*          biasf = (float*)(ws + (64u << 20) + (64u << 10));
    unsigned short* WT    = (unsigned short*)(ws + (64u << 20) + (128u << 10));
    unsigned short* HsT   = (unsigned short*)(ws + (64u << 20) + (256u << 10));
    unsigned short* Xa    = (unsigned short*)(ws + (68u << 20) + (256u << 10));
    unsigned short* X2    = (unsigned short*)(ws + (72u << 20) + (256u << 10));

    k_pre<<<16578, 256, 0, stream>>>(adj, W1, W2, W3, b1, b2, b3, dinv, adjb, WT, biasf);

    // layer 1
    k_gxw<1><<<512, 256, 0, stream>>>(X, WT, biasf, dinv, HsT);
    k_gah<1, 0><<<512, 256, 0, stream>>>(adjb, HsT, dinv, nullptr, Xa);
    // layer 2 (residual = Xa)
    k_gxw<0><<<512, 256, 0, stream>>>(Xa, WT + 16384, biasf + 128, dinv, HsT);
    k_gah<2, 0><<<512, 256, 0, stream>>>(adjb, HsT, dinv, Xa, X2);
    // layer 3 -> fp32 out
    k_gxw<0><<<512, 256, 0, stream>>>(X2, WT + 32768, biasf + 256, dinv, HsT);
    k_gah<1, 1><<<512, 256, 0, stream>>>(adjb, HsT, dinv, nullptr, (float*)d_out);
}